// Round 5
// baseline (243.980 us; speedup 1.0000x reference)
//
#include <hip/hip_runtime.h>
#include <cstdint>
#include <cstddef>

#define N_TOK 2048
#define HID 1024
#define FDIM 1024
#define NE 8
#define PAIR_CAP 5120
#define MT 128
#define BK 64
#define THRESH 0.7f

typedef __attribute__((ext_vector_type(8))) short bf16x8;
typedef __attribute__((ext_vector_type(4))) float f32x4;

static __device__ __forceinline__ unsigned short f2bf(float f) {
  unsigned int u = __float_as_uint(f);
  u += 0x7FFF + ((u >> 16) & 1);   // RNE
  return (unsigned short)(u >> 16);
}

// async global->LDS, 16B per lane; lds dest = wave-uniform base + lane*16
static __device__ __forceinline__ void gl2lds16(const unsigned short* g, unsigned short* l) {
  __builtin_amdgcn_global_load_lds(
      (const __attribute__((address_space(1))) void*)g,
      (__attribute__((address_space(3))) void*)l, 16, 0, 0);
}

// ---------------- Router: fp32 logits -> softmax -> top2 (+norm); x -> bf16
__global__ __launch_bounds__(256) void k_router(
    const float* __restrict__ x, const float* __restrict__ gw,
    unsigned short* __restrict__ xb, float* __restrict__ topw,
    int* __restrict__ topi) {
  __shared__ float sgw[NE * HID];
  int t = threadIdx.x;
#pragma unroll
  for (int i = 0; i < NE * HID / 256; ++i) sgw[t + 256 * i] = gw[t + 256 * i];
  __syncthreads();
  int lane = t & 63;
  int wave = t >> 6;
  int n = blockIdx.x * 4 + wave;
  float acc[NE];
#pragma unroll
  for (int e = 0; e < NE; ++e) acc[e] = 0.f;
#pragma unroll
  for (int i = 0; i < HID / 64; ++i) {
    int h = i * 64 + lane;
    float xv = x[(size_t)n * HID + h];
    xb[(size_t)n * HID + h] = f2bf(xv);
#pragma unroll
    for (int e = 0; e < NE; ++e) acc[e] += xv * sgw[e * HID + h];
  }
#pragma unroll
  for (int off = 32; off > 0; off >>= 1) {
#pragma unroll
    for (int e = 0; e < NE; ++e) acc[e] += __shfl_xor(acc[e], off, 64);
  }
  if (lane == 0) {
    float m = acc[0];
    for (int e = 1; e < NE; ++e) m = fmaxf(m, acc[e]);
    float p[NE]; float s = 0.f;
    for (int e = 0; e < NE; ++e) { p[e] = __expf(acc[e] - m); s += p[e]; }
    float inv = 1.f / s;
    for (int e = 0; e < NE; ++e) p[e] *= inv;
    int i0 = 0; float b0 = p[0];
    for (int e = 1; e < NE; ++e) if (p[e] > b0) { b0 = p[e]; i0 = e; }
    int i1 = -1; float b1 = -1.f;
    for (int e = 0; e < NE; ++e) { if (e == i0) continue; if (p[e] > b1) { b1 = p[e]; i1 = e; } }
    float sw = b0 + b1; if (sw < 1e-12f) sw = 1e-12f;
    topw[n * 2] = b0 / sw; topw[n * 2 + 1] = b1 / sw;
    topi[n * 2] = i0;      topi[n * 2 + 1] = i1;
  }
}

// ---------------- Pairs: primary mask from top-1s, expert_map, compact slot lists
__global__ __launch_bounds__(256) void k_pairs(
    const float* __restrict__ sim, const int* __restrict__ topi,
    const float* __restrict__ topw, int* __restrict__ ctrl,
    int* __restrict__ ptok, float* __restrict__ pw) {
  __shared__ int prim[NE], emap[NE], cnt[NE], soff[NE], cur[NE], padc[NE];
  int t = threadIdx.x;
  if (t < NE) { prim[t] = 0; cnt[t] = 0; }
  __syncthreads();
  for (int n = t; n < N_TOK; n += 256) prim[topi[n * 2]] = 1;   // S=1: union of top-1
  __syncthreads();
  if (t < NE) {
    float best = -1e30f; int bj = -1;
    for (int j = 0; j < NE; ++j) {
      if (prim[j]) {
        float s = sim[t * NE + j];
        if (s > best) { best = s; bj = j; }   // strict >: first-index argmax like jnp
      }
    }
    int m = t;
    if (!prim[t] && bj >= 0 && best >= THRESH) m = bj;
    emap[t] = m;
  }
  __syncthreads();
  for (int n = t; n < N_TOK; n += 256) {
    atomicAdd(&cnt[emap[topi[n * 2]]], 1);
    atomicAdd(&cnt[emap[topi[n * 2 + 1]]], 1);
  }
  __syncthreads();
  if (t == 0) {
    int o = 0;
    for (int e = 0; e < NE; ++e) {
      soff[e] = o;
      int p = (cnt[e] + MT - 1) & ~(MT - 1);
      padc[e] = p; cur[e] = 0; o += p;
    }
  }
  __syncthreads();
  if (t < NE) { ctrl[24 + t] = soff[t]; ctrl[32 + t] = padc[t]; }
  for (int n = t; n < N_TOK; n += 256) {
    int i0 = topi[n * 2], i1 = topi[n * 2 + 1];
    int e0 = emap[i0], e1 = emap[i1];
    int s0 = soff[e0] + atomicAdd(&cur[e0], 1);
    int s1 = soff[e1] + atomicAdd(&cur[e1], 1);
    ptok[s0] = n; pw[s0] = topw[n * 2];
    ptok[s1] = n; pw[s1] = topw[n * 2 + 1];
  }
  __syncthreads();
  for (int e = 0; e < NE; ++e) {
    for (int s = cnt[e] + t; s < padc[e]; s += 256) {
      ptok[soff[e] + s] = 0; pw[soff[e] + s] = 0.f;   // padding: token 0, weight 0
    }
  }
}

// LDS layout both GEMMs: rows x 8 chunks of 16B (64 bf16). Physical chunk of
// row r holds logical chunk p ^ (r&7): async A-writes stay lane-contiguous,
// fragment ds_read_b128 sees only 2-way bank aliasing (free, m136).
// NOTE: __launch_bounds__ 2nd arg MUST stay 2 — (256,4) crashed the container
// in rounds 2 and 4 (A/B-isolated vs round 3's identical (256,2) kernel).

// ---------------- GEMM1: M128 x N64(f) tile; A=xb bf16 async-LDS, B=gup fp32
// register-batched cvt.
__global__ __launch_bounds__(256, 2) void k_gemm1(
    const unsigned short* __restrict__ xb, const float* __restrict__ gup,
    unsigned short* __restrict__ hmid, const int* __restrict__ ptok,
    const int* __restrict__ ctrl) {
  // b = mt*256 + e*32 + y : same (e,y) across mt -> same XCD (256 % 8 == 0)
  int b = blockIdx.x;
  int mt = b >> 8;
  int r8 = b & 255;
  int e = r8 >> 5;
  int y = r8 & 31;
  int padc = ctrl[32 + e];
  if (mt * MT >= padc) return;
  int base = ctrl[24 + e] + mt * MT;
  int f0 = y * 32;   // 32 f-values (gate+up pairs), 64 B-rows

  __shared__ unsigned short As[MT * BK];
  __shared__ unsigned short Bs[64 * BK];
  __shared__ int toks[MT];

  int t = threadIdx.x;
  if (t < MT) toks[t] = ptok[base + t];
  __syncthreads();

  int lane = t & 63;
  int wave = t >> 6;
  int wm = wave >> 1, wn = wave & 1;
  int lm = lane & 15, lh = lane >> 4;

  f32x4 acc[4][2] = {};
  const float* gbase = gup + (size_t)e * 2 * FDIM * HID;

  for (int k0 = 0; k0 < HID; k0 += BK) {
    // B: 64 rows x 64 fp32 -> 4 float4/thread, batched loads then cvt
    float4 vb[4];
#pragma unroll
    for (int i = 0; i < 4; ++i) {
      int q = i * 256 + t;
      int r = q >> 4, c4 = q & 15;
      vb[i] = *(const float4*)(gbase + (size_t)(((r >> 4) & 1) * FDIM + f0 + ((r >> 5) << 4) + (r & 15)) * HID + k0 + c4 * 4);
    }
    // A: 128 rows x 64 bf16, async token gather
#pragma unroll
    for (int i = 0; i < 4; ++i) {
      int q = i * 256 + t;
      int r = q >> 3;
      int cl = (q & 7) ^ (r & 7);
      gl2lds16(xb + (size_t)toks[r] * HID + k0 + cl * 8, &As[(q & ~63) * 8]);
    }
#pragma unroll
    for (int i = 0; i < 4; ++i) {
      int q = i * 256 + t;
      int r = q >> 4, w = q & 15;           // 8B unit w within row
      int pch = (w >> 1) ^ (r & 7);         // 16B chunk swizzle
      unsigned long long pk = (unsigned long long)f2bf(vb[i].x)
          | ((unsigned long long)f2bf(vb[i].y) << 16)
          | ((unsigned long long)f2bf(vb[i].z) << 32)
          | ((unsigned long long)f2bf(vb[i].w) << 48);
      *(unsigned long long*)(&Bs[r * BK + pch * 8 + (w & 1) * 4]) = pk;
    }
    __syncthreads();
#pragma unroll
    for (int kk = 0; kk < 2; ++kk) {
      bf16x8 af[4], bfr[2];
#pragma unroll
      for (int rb = 0; rb < 4; ++rb) {
        int row = wm * 64 + rb * 16 + lm;
        int p = (kk * 4 + lh) ^ (row & 7);
        af[rb] = *(const bf16x8*)(&As[row * BK + p * 8]);
      }
#pragma unroll
      for (int cc = 0; cc < 2; ++cc) {
        int row = wn * 32 + cc * 16 + lm;
        int p = (kk * 4 + lh) ^ (row & 7);
        bfr[cc] = *(const bf16x8*)(&Bs[row * BK + p * 8]);
      }
#pragma unroll
      for (int rb = 0; rb < 4; ++rb) {
#pragma unroll
        for (int cc = 0; cc < 2; ++cc)
          acc[rb][cc] = __builtin_amdgcn_mfma_f32_16x16x32_bf16(af[rb], bfr[cc], acc[rb][cc], 0, 0, 0);
      }
    }
    __syncthreads();
  }
  // epilogue: cc=0 gate rows, cc=1 up rows (same f); f = f0 + wn*16 + lm
#pragma unroll
  for (int rb = 0; rb < 4; ++rb) {
    int slot = base + wm * 64 + rb * 16 + lh * 4;
    f32x4 g = acc[rb][0];
    f32x4 u = acc[rb][1];
    int f = f0 + wn * 16 + lm;
#pragma unroll
    for (int reg = 0; reg < 4; ++reg) {
      float gv = g[reg];
      float hm = gv / (1.f + __expf(-gv)) * u[reg];
      hmid[(size_t)(slot + reg) * FDIM + f] = f2bf(hm);
    }
  }
}

// ---------------- GEMM2: M128 x N64(h); A=hmid bf16 async, B=dwn fp32 batched;
// epilogue fused combine: atomicAdd(out[token][h], pw[slot]*acc)
__global__ __launch_bounds__(256, 2) void k_gemm2(
    const unsigned short* __restrict__ hmid, const float* __restrict__ dwn,
    float* __restrict__ out, const int* __restrict__ ptok,
    const float* __restrict__ pw, const int* __restrict__ ctrl) {
  // b = mt*128 + e*16 + y
  int b = blockIdx.x;
  int mt = b >> 7;
  int r7 = b & 127;
  int e = r7 >> 4;
  int y = r7 & 15;
  int padc = ctrl[32 + e];
  if (mt * MT >= padc) return;
  int base = ctrl[24 + e] + mt * MT;
  int h0 = y * 64;

  __shared__ unsigned short As[MT * BK];
  __shared__ unsigned short Bs[64 * BK];
  __shared__ int stok[MT];
  __shared__ float spw[MT];

  int t = threadIdx.x;
  if (t < MT) { stok[t] = ptok[base + t]; spw[t] = pw[base + t]; }
  __syncthreads();

  int lane = t & 63;
  int wave = t >> 6;
  int wm = wave >> 1, wn = wave & 1;
  int lm = lane & 15, lh = lane >> 4;

  f32x4 acc[4][2] = {};
  const float* dbase = dwn + (size_t)e * HID * FDIM;

  for (int k0 = 0; k0 < FDIM; k0 += BK) {
    float4 vb[4];
#pragma unroll
    for (int i = 0; i < 4; ++i) {
      int q = i * 256 + t;
      int r = q >> 4, c4 = q & 15;
      vb[i] = *(const float4*)(dbase + (size_t)(h0 + r) * FDIM + k0 + c4 * 4);
    }
#pragma unroll
    for (int i = 0; i < 4; ++i) {
      int q = i * 256 + t;
      int r = q >> 3;
      int cl = (q & 7) ^ (r & 7);
      gl2lds16(hmid + (size_t)(base + r) * FDIM + k0 + cl * 8, &As[(q & ~63) * 8]);
    }
#pragma unroll
    for (int i = 0; i < 4; ++i) {
      int q = i * 256 + t;
      int r = q >> 4, w = q & 15;
      int pch = (w >> 1) ^ (r & 7);
      unsigned long long pk = (unsigned long long)f2bf(vb[i].x)
          | ((unsigned long long)f2bf(vb[i].y) << 16)
          | ((unsigned long long)f2bf(vb[i].z) << 32)
          | ((unsigned long long)f2bf(vb[i].w) << 48);
      *(unsigned long long*)(&Bs[r * BK + pch * 8 + (w & 1) * 4]) = pk;
    }
    __syncthreads();
#pragma unroll
    for (int kk = 0; kk < 2; ++kk) {
      bf16x8 af[4], bfr[2];
#pragma unroll
      for (int rb = 0; rb < 4; ++rb) {
        int row = wm * 64 + rb * 16 + lm;
        int p = (kk * 4 + lh) ^ (row & 7);
        af[rb] = *(const bf16x8*)(&As[row * BK + p * 8]);
      }
#pragma unroll
      for (int cc = 0; cc < 2; ++cc) {
        int row = wn * 32 + cc * 16 + lm;
        int p = (kk * 4 + lh) ^ (row & 7);
        bfr[cc] = *(const bf16x8*)(&Bs[row * BK + p * 8]);
      }
#pragma unroll
      for (int rb = 0; rb < 4; ++rb) {
#pragma unroll
        for (int cc = 0; cc < 2; ++cc)
          acc[rb][cc] = __builtin_amdgcn_mfma_f32_16x16x32_bf16(af[rb], bfr[cc], acc[rb][cc], 0, 0, 0);
      }
    }
    __syncthreads();
  }
  // fused combine: out[token][h] += w * acc   (out pre-zeroed)
#pragma unroll
  for (int rb = 0; rb < 4; ++rb) {
    int sl = wm * 64 + rb * 16 + lh * 4;
#pragma unroll
    for (int cc = 0; cc < 2; ++cc) {
      int h = h0 + wn * 32 + cc * 16 + lm;
#pragma unroll
      for (int reg = 0; reg < 4; ++reg) {
        int tok = stok[sl + reg];
        float wgt = spw[sl + reg];
        atomicAdd(&out[(size_t)tok * HID + h], wgt * acc[rb][cc][reg]);
      }
    }
  }
}

extern "C" void kernel_launch(void* const* d_in, const int* in_sizes, int n_in,
                              void* d_out, int out_size, void* d_ws, size_t ws_size,
                              hipStream_t stream) {
  (void)in_sizes; (void)n_in; (void)ws_size;
  const float* x   = (const float*)d_in[0];
  const float* gw  = (const float*)d_in[1];
  const float* gup = (const float*)d_in[2];
  const float* dwn = (const float*)d_in[3];
  const float* sim = (const float*)d_in[4];
  float* out = (float*)d_out;

  char* w = (char*)d_ws;
  int* ctrl = (int*)w;
  size_t off = 256;
  unsigned short* xb = (unsigned short*)(w + off); off += (size_t)N_TOK * HID * 2;
  float* topw = (float*)(w + off); off += (size_t)N_TOK * 2 * 4;
  int*   topi = (int*)(w + off);   off += (size_t)N_TOK * 2 * 4;
  int*   ptok = (int*)(w + off);   off += (size_t)PAIR_CAP * 4;
  float* pw   = (float*)(w + off); off += (size_t)PAIR_CAP * 4;
  unsigned short* hmid = (unsigned short*)(w + off); off += (size_t)PAIR_CAP * FDIM * 2;
  // total ~14.8 MB

  hipMemsetAsync(out, 0, (size_t)out_size * 4, stream);
  k_router<<<N_TOK / 4, 256, 0, stream>>>(x, gw, xb, topw, topi);
  k_pairs<<<1, 256, 0, stream>>>(sim, topi, topw, ctrl, ptok, pw);
  k_gemm1<<<dim3(32 * 256), 256, 0, stream>>>(xb, gup, hmid, ptok, ctrl);
  k_gemm2<<<dim3(32 * 128), 256, 0, stream>>>(hmid, dwn, out, ptok, pw, ctrl);
}

// Round 7
// 212.628 us; speedup vs baseline: 1.1475x; 1.1475x over previous
//
#include <hip/hip_runtime.h>
#include <cstdint>
#include <cstddef>

#define N_TOK 2048
#define HID 1024
#define FDIM 1024
#define NE 8
#define PAIR_CAP 5120
#define MT 128
#define BK 64
#define THRESH 0.7f

typedef __attribute__((ext_vector_type(8))) short bf16x8;
typedef __attribute__((ext_vector_type(4))) float f32x4;

static __device__ __forceinline__ unsigned short f2bf(float f) {
  unsigned int u = __float_as_uint(f);
  u += 0x7FFF + ((u >> 16) & 1);   // RNE
  return (unsigned short)(u >> 16);
}
static __device__ __forceinline__ float bf2f(unsigned short u) {
  return __uint_as_float(((unsigned int)u) << 16);
}

// async global->LDS, 16B per lane; lds dest = wave-uniform base + lane*16
static __device__ __forceinline__ void gl2lds16(const unsigned short* g, unsigned short* l) {
  __builtin_amdgcn_global_load_lds(
      (const __attribute__((address_space(1))) void*)g,
      (__attribute__((address_space(3))) void*)l, 16, 0, 0);
}

// ---------------- fp32 -> bf16 weight conversion (R3-proven kernel)
__global__ __launch_bounds__(256) void k_cvt(
    const float* __restrict__ src, unsigned short* __restrict__ dst, int n4) {
  int i = blockIdx.x * 256 + threadIdx.x;
  if (i < n4) {
    float4 v = ((const float4*)src)[i];
    ushort4 o;
    o.x = f2bf(v.x); o.y = f2bf(v.y); o.z = f2bf(v.z); o.w = f2bf(v.w);
    ((ushort4*)dst)[i] = o;
  }
}

// ---------------- Router: fp32 logits -> softmax -> top2 (+norm); x -> bf16
__global__ __launch_bounds__(256) void k_router(
    const float* __restrict__ x, const float* __restrict__ gw,
    unsigned short* __restrict__ xb, float* __restrict__ topw,
    int* __restrict__ topi) {
  __shared__ float sgw[NE * HID];
  int t = threadIdx.x;
#pragma unroll
  for (int i = 0; i < NE * HID / 256; ++i) sgw[t + 256 * i] = gw[t + 256 * i];
  __syncthreads();
  int lane = t & 63;
  int wave = t >> 6;
  int n = blockIdx.x * 4 + wave;
  float acc[NE];
#pragma unroll
  for (int e = 0; e < NE; ++e) acc[e] = 0.f;
#pragma unroll
  for (int i = 0; i < HID / 64; ++i) {
    int h = i * 64 + lane;
    float xv = x[(size_t)n * HID + h];
    xb[(size_t)n * HID + h] = f2bf(xv);
#pragma unroll
    for (int e = 0; e < NE; ++e) acc[e] += xv * sgw[e * HID + h];
  }
#pragma unroll
  for (int off = 32; off > 0; off >>= 1) {
#pragma unroll
    for (int e = 0; e < NE; ++e) acc[e] += __shfl_xor(acc[e], off, 64);
  }
  if (lane == 0) {
    float m = acc[0];
    for (int e = 1; e < NE; ++e) m = fmaxf(m, acc[e]);
    float p[NE]; float s = 0.f;
    for (int e = 0; e < NE; ++e) { p[e] = __expf(acc[e] - m); s += p[e]; }
    float inv = 1.f / s;
    for (int e = 0; e < NE; ++e) p[e] *= inv;
    int i0 = 0; float b0 = p[0];
    for (int e = 1; e < NE; ++e) if (p[e] > b0) { b0 = p[e]; i0 = e; }
    int i1 = -1; float b1 = -1.f;
    for (int e = 0; e < NE; ++e) { if (e == i0) continue; if (p[e] > b1) { b1 = p[e]; i1 = e; } }
    float sw = b0 + b1; if (sw < 1e-12f) sw = 1e-12f;
    topw[n * 2] = b0 / sw; topw[n * 2 + 1] = b1 / sw;
    topi[n * 2] = i0;      topi[n * 2 + 1] = i1;
  }
}

// ---------------- Pairs: primary mask, expert_map, compact slot lists (+pot)
__global__ __launch_bounds__(256) void k_pairs(
    const float* __restrict__ sim, const int* __restrict__ topi,
    const float* __restrict__ topw, int* __restrict__ ctrl,
    int* __restrict__ ptok, float* __restrict__ pw, int* __restrict__ pot) {
  __shared__ int prim[NE], emap[NE], cnt[NE], soff[NE], cur[NE], padc[NE];
  int t = threadIdx.x;
  if (t < NE) { prim[t] = 0; cnt[t] = 0; }
  __syncthreads();
  for (int n = t; n < N_TOK; n += 256) prim[topi[n * 2]] = 1;   // S=1: union of top-1
  __syncthreads();
  if (t < NE) {
    float best = -1e30f; int bj = -1;
    for (int j = 0; j < NE; ++j) {
      if (prim[j]) {
        float s = sim[t * NE + j];
        if (s > best) { best = s; bj = j; }   // strict >: first-index argmax like jnp
      }
    }
    int m = t;
    if (!prim[t] && bj >= 0 && best >= THRESH) m = bj;
    emap[t] = m;
  }
  __syncthreads();
  for (int n = t; n < N_TOK; n += 256) {
    atomicAdd(&cnt[emap[topi[n * 2]]], 1);
    atomicAdd(&cnt[emap[topi[n * 2 + 1]]], 1);
  }
  __syncthreads();
  if (t == 0) {
    int o = 0;
    for (int e = 0; e < NE; ++e) {
      soff[e] = o;
      int p = (cnt[e] + MT - 1) & ~(MT - 1);
      padc[e] = p; cur[e] = 0; o += p;
    }
  }
  __syncthreads();
  if (t < NE) { ctrl[24 + t] = soff[t]; ctrl[32 + t] = padc[t]; }
  for (int n = t; n < N_TOK; n += 256) {
    int i0 = topi[n * 2], i1 = topi[n * 2 + 1];
    int e0 = emap[i0], e1 = emap[i1];
    int s0 = soff[e0] + atomicAdd(&cur[e0], 1);
    int s1 = soff[e1] + atomicAdd(&cur[e1], 1);
    ptok[s0] = n; pw[s0] = topw[n * 2];
    ptok[s1] = n; pw[s1] = topw[n * 2 + 1];
    pot[n * 2] = s0; pot[n * 2 + 1] = s1;
  }
  __syncthreads();
  for (int e = 0; e < NE; ++e) {
    for (int s = cnt[e] + t; s < padc[e]; s += 256) {
      ptok[soff[e] + s] = 0; pw[soff[e] + s] = 0.f;   // padding: token 0, weight 0
    }
  }
}

// LDS layout both GEMMs: rows x 8 chunks of 16B (64 bf16). Physical chunk of
// row r holds logical chunk p ^ (r&7): async writes stay lane-contiguous,
// fragment ds_read_b128 sees only 2-way bank aliasing (free, m136).
// Launch bounds (256,2): the only config that has never crashed the container.

// ---------------- GEMM1: M128 x 64 B-rows (32 f gate+up); all-async staging
__global__ __launch_bounds__(256, 2) void k_gemm1(
    const unsigned short* __restrict__ xb, const unsigned short* __restrict__ gupb,
    unsigned short* __restrict__ hmid, const int* __restrict__ ptok,
    const int* __restrict__ ctrl) {
  // b = mt*256 + e*32 + y : same (e,y) across mt -> same XCD (256 % 8 == 0)
  int b = blockIdx.x;
  int mt = b >> 8;
  int r8 = b & 255;
  int e = r8 >> 5;
  int y = r8 & 31;
  int padc = ctrl[32 + e];
  if (mt * MT >= padc) return;
  int base = ctrl[24 + e] + mt * MT;
  int f0 = y * 32;

  __shared__ unsigned short As[MT * BK];   // 16 KB
  __shared__ unsigned short Bs[64 * BK];   // 8 KB
  __shared__ int toks[MT];

  int t = threadIdx.x;
  if (t < MT) toks[t] = ptok[base + t];
  __syncthreads();

  int lane = t & 63;
  int wave = t >> 6;
  int wm = wave >> 1, wn = wave & 1;
  int lm = lane & 15, lh = lane >> 4;

  f32x4 acc[4][2] = {};
  const unsigned short* gbase = gupb + (size_t)e * 2 * FDIM * HID;

  for (int k0 = 0; k0 < HID; k0 += BK) {
    // A: 128 rows x 64 bf16, async token gather
#pragma unroll
    for (int i = 0; i < 4; ++i) {
      int q = i * 256 + t;
      int r = q >> 3;
      int cl = (q & 7) ^ (r & 7);
      gl2lds16(xb + (size_t)toks[r] * HID + k0 + cl * 8, &As[(q & ~63) * 8]);
    }
    // B: 64 rows (gate/up x 16-f groups) x 64 bf16, async
#pragma unroll
    for (int i = 0; i < 2; ++i) {
      int q = i * 256 + t;
      int r = q >> 3;
      int cl = (q & 7) ^ (r & 7);
      int grow = ((r >> 4) & 1) * FDIM + f0 + ((r >> 5) << 4) + (r & 15);
      gl2lds16(gbase + (size_t)grow * HID + k0 + cl * 8, &Bs[(q & ~63) * 8]);
    }
    __syncthreads();
#pragma unroll
    for (int kk = 0; kk < 2; ++kk) {
      bf16x8 af[4], bfr[2];
#pragma unroll
      for (int rb = 0; rb < 4; ++rb) {
        int row = wm * 64 + rb * 16 + lm;
        int p = (kk * 4 + lh) ^ (row & 7);
        af[rb] = *(const bf16x8*)(&As[row * BK + p * 8]);
      }
#pragma unroll
      for (int cc = 0; cc < 2; ++cc) {
        int row = wn * 32 + cc * 16 + lm;
        int p = (kk * 4 + lh) ^ (row & 7);
        bfr[cc] = *(const bf16x8*)(&Bs[row * BK + p * 8]);
      }
#pragma unroll
      for (int rb = 0; rb < 4; ++rb) {
#pragma unroll
        for (int cc = 0; cc < 2; ++cc)
          acc[rb][cc] = __builtin_amdgcn_mfma_f32_16x16x32_bf16(af[rb], bfr[cc], acc[rb][cc], 0, 0, 0);
      }
    }
    __syncthreads();
  }
  // epilogue: cc=0 gate, cc=1 up (same f); f = f0 + wn*16 + lm
#pragma unroll
  for (int rb = 0; rb < 4; ++rb) {
    int slot = base + wm * 64 + rb * 16 + lh * 4;
    f32x4 g = acc[rb][0];
    f32x4 u = acc[rb][1];
    int f = f0 + wn * 16 + lm;
#pragma unroll
    for (int reg = 0; reg < 4; ++reg) {
      float gv = g[reg];
      float hm = gv / (1.f + __expf(-gv)) * u[reg];
      hmid[(size_t)(slot + reg) * FDIM + f] = f2bf(hm);
    }
  }
}

// ---------------- GEMM2: M128 x N32(h); all-async staging; yb bf16 out
__global__ __launch_bounds__(256, 2) void k_gemm2(
    const unsigned short* __restrict__ hmid, const unsigned short* __restrict__ dwnb,
    unsigned short* __restrict__ yb, const int* __restrict__ ctrl) {
  // b = mt*256 + e*32 + y
  int b = blockIdx.x;
  int mt = b >> 8;
  int r8 = b & 255;
  int e = r8 >> 5;
  int y = r8 & 31;
  int padc = ctrl[32 + e];
  if (mt * MT >= padc) return;
  int base = ctrl[24 + e] + mt * MT;
  int h0 = y * 32;

  __shared__ unsigned short As[MT * BK];   // 16 KB
  __shared__ unsigned short Bs[32 * BK];   // 4 KB

  int t = threadIdx.x;
  int lane = t & 63;
  int wave = t >> 6;
  int wm = wave >> 1, wn = wave & 1;
  int lm = lane & 15, lh = lane >> 4;

  f32x4 acc[4] = {};
  const unsigned short* dbase = dwnb + (size_t)e * HID * FDIM;

  for (int k0 = 0; k0 < FDIM; k0 += BK) {
#pragma unroll
    for (int i = 0; i < 4; ++i) {
      int q = i * 256 + t;
      int r = q >> 3;
      int cl = (q & 7) ^ (r & 7);
      gl2lds16(hmid + (size_t)(base + r) * FDIM + k0 + cl * 8, &As[(q & ~63) * 8]);
    }
    {
      int q = t;                       // 32 rows x 8 chunks = 256 slots
      int r = q >> 3;
      int cl = (q & 7) ^ (r & 7);
      gl2lds16(dbase + (size_t)(h0 + r) * FDIM + k0 + cl * 8, &Bs[(q & ~63) * 8]);
    }
    __syncthreads();
#pragma unroll
    for (int kk = 0; kk < 2; ++kk) {
      bf16x8 af[4], bfr;
#pragma unroll
      for (int rb = 0; rb < 4; ++rb) {
        int row = wm * 64 + rb * 16 + lm;
        int p = (kk * 4 + lh) ^ (row & 7);
        af[rb] = *(const bf16x8*)(&As[row * BK + p * 8]);
      }
      {
        int row = wn * 16 + lm;
        int p = (kk * 4 + lh) ^ (row & 7);
        bfr = *(const bf16x8*)(&Bs[row * BK + p * 8]);
      }
#pragma unroll
      for (int rb = 0; rb < 4; ++rb)
        acc[rb] = __builtin_amdgcn_mfma_f32_16x16x32_bf16(af[rb], bfr, acc[rb], 0, 0, 0);
    }
    __syncthreads();
  }
#pragma unroll
  for (int rb = 0; rb < 4; ++rb) {
    int slot = base + wm * 64 + rb * 16 + lh * 4;
    int h = h0 + wn * 16 + lm;
#pragma unroll
    for (int reg = 0; reg < 4; ++reg)
      yb[(size_t)(slot + reg) * HID + h] = f2bf(acc[rb][reg]);
  }
}

// ---------------- Combine: out[n] = w0*y[p0] + w1*y[p1]
__global__ __launch_bounds__(256) void k_combine(
    const unsigned short* __restrict__ yb, const float* __restrict__ pw,
    const int* __restrict__ pot, float* __restrict__ out) {
  int n = blockIdx.x;
  int t = threadIdx.x;
  int p0 = pot[n * 2], p1 = pot[n * 2 + 1];
  float w0 = pw[p0], w1 = pw[p1];
  int h = t * 4;
  ushort4 a = *(const ushort4*)(yb + (size_t)p0 * HID + h);
  ushort4 b = *(const ushort4*)(yb + (size_t)p1 * HID + h);
  float4 o;
  o.x = w0 * bf2f(a.x) + w1 * bf2f(b.x);
  o.y = w0 * bf2f(a.y) + w1 * bf2f(b.y);
  o.z = w0 * bf2f(a.z) + w1 * bf2f(b.z);
  o.w = w0 * bf2f(a.w) + w1 * bf2f(b.w);
  *(float4*)(out + (size_t)n * HID + h) = o;
}

extern "C" void kernel_launch(void* const* d_in, const int* in_sizes, int n_in,
                              void* d_out, int out_size, void* d_ws, size_t ws_size,
                              hipStream_t stream) {
  (void)in_sizes; (void)n_in; (void)out_size; (void)ws_size;
  const float* x   = (const float*)d_in[0];
  const float* gw  = (const float*)d_in[1];
  const float* gup = (const float*)d_in[2];
  const float* dwn = (const float*)d_in[3];
  const float* sim = (const float*)d_in[4];
  float* out = (float*)d_out;

  char* w = (char*)d_ws;
  int* ctrl = (int*)w;
  size_t off = 256;
  unsigned short* xb = (unsigned short*)(w + off); off += (size_t)N_TOK * HID * 2;
  float* topw = (float*)(w + off); off += (size_t)N_TOK * 2 * 4;
  int*   topi = (int*)(w + off);   off += (size_t)N_TOK * 2 * 4;
  int*   ptok = (int*)(w + off);   off += (size_t)PAIR_CAP * 4;
  float* pw   = (float*)(w + off); off += (size_t)PAIR_CAP * 4;
  int*   pot  = (int*)(w + off);   off += (size_t)N_TOK * 2 * 4;
  unsigned short* hmid = (unsigned short*)(w + off); off += (size_t)PAIR_CAP * FDIM * 2;
  unsigned short* yb   = (unsigned short*)(w + off); off += (size_t)PAIR_CAP * HID * 2;
  unsigned short* gupb = (unsigned short*)(w + off); off += (size_t)NE * 2 * FDIM * HID * 2;
  unsigned short* dwnb = (unsigned short*)(w + off); off += (size_t)NE * HID * FDIM * 2;
  // total ~73 MB; ws measured ~268 MB (round-3 fill WRITE_SIZE)

  int n4g = NE * 2 * FDIM * HID / 4;
  int n4d = NE * HID * FDIM / 4;
  k_cvt<<<(n4g + 255) / 256, 256, 0, stream>>>(gup, gupb, n4g);
  k_cvt<<<(n4d + 255) / 256, 256, 0, stream>>>(dwn, dwnb, n4d);
  k_router<<<N_TOK / 4, 256, 0, stream>>>(x, gw, xb, topw, topi);
  k_pairs<<<1, 256, 0, stream>>>(sim, topi, topw, ctrl, ptok, pw, pot);
  k_gemm1<<<dim3(32 * 256), 256, 0, stream>>>(xb, gupb, hmid, ptok, ctrl);
  k_gemm2<<<dim3(32 * 256), 256, 0, stream>>>(hmid, dwnb, yb, ctrl);
  k_combine<<<N_TOK, 256, 0, stream>>>(yb, pw, pot, out);
}